// Round 1
// baseline (511.658 us; speedup 1.0000x reference)
//
#include <hip/hip_runtime.h>
#include <hip/hip_bf16.h>
#include <math.h>

// Problem constants
#define SEQ 2048
#define DIM 4096
#define NH 32
#define NKV 8
#define HD 128
#define KVD 1024              // NKV*HD
#define SCALE 0.08838834764831845f
#define NEGBIG -1000000000.0f

typedef __bf16 bf16;
typedef __attribute__((ext_vector_type(4))) __bf16 bf16x4;
typedef __attribute__((ext_vector_type(8))) __bf16 bf16x8;
typedef __attribute__((ext_vector_type(4))) float f32x4;

// ---------------------------------------------------------------------------
// async global->LDS 16B copy (wave-uniform LDS base + lane*16 semantics)
__device__ __forceinline__ void async_g2l16(const bf16* g, bf16* l) {
  __builtin_amdgcn_global_load_lds(
      (const __attribute__((address_space(1))) void*)g,
      (__attribute__((address_space(3))) void*)l,
      16, 0, 0);
}

// ---------------------------------------------------------------------------
// fused fp32 -> bf16 cast for all 5 tensors, float4 vectorized, 1 launch
#define SEG_X  2097152            // SEQ*DIM/4
#define SEG_WQ 4194304            // DIM*DIM/4
#define SEG_WK 1048576            // KVD*DIM/4
#define C0 SEG_X
#define C1 (C0 + SEG_WQ)
#define C2 (C1 + SEG_WK)
#define C3 (C2 + SEG_WK)
#define C4 (C3 + SEG_WQ)          // 12582912 total float4

__global__ void cast_all_kernel(const float* __restrict__ x,
                                const float* __restrict__ wq,
                                const float* __restrict__ wk,
                                const float* __restrict__ wv,
                                const float* __restrict__ wo,
                                bf16* __restrict__ xb, bf16* __restrict__ wqb,
                                bf16* __restrict__ wkb, bf16* __restrict__ wvb,
                                bf16* __restrict__ wob) {
  int i = blockIdx.x * 256 + threadIdx.x;
  const float* src; bf16* dst; int j;
  if (i < C0)      { src = x;  dst = xb;  j = i; }
  else if (i < C1) { src = wq; dst = wqb; j = i - C0; }
  else if (i < C2) { src = wk; dst = wkb; j = i - C1; }
  else if (i < C3) { src = wv; dst = wvb; j = i - C2; }
  else             { src = wo; dst = wob; j = i - C3; }
  float4 v = ((const float4*)src)[j];
  bf16x4 o;
  o[0] = (bf16)v.x; o[1] = (bf16)v.y; o[2] = (bf16)v.z; o[3] = (bf16)v.w;
  ((bf16x4*)dst)[j] = o;
}

// ---------------------------------------------------------------------------
// 256x256 tile, BK=64, 8-wave (2Mx4N), 8-phase counted-vmcnt GEMM core.
//
// Schedule (one iteration = 2 K-tiles, buf0 then buf1; 4 quadrant-phases per
// K-tile in Gray order Q(rh0,ch0) Q(rh0,ch1) Q(rh1,ch1) Q(rh1,ch0)):
//   p1: ds_read A-rh0(8)+B-ch0(4) | stage A(buf1, kt 2i+1) | bar | 16 MFMA | bar
//   p2: ds_read B-ch1(4)          | -                      | bar | 16 MFMA | bar
//   p3: ds_read A-rh1(8)          | stage B0(buf0, 2i+2)   | bar | 16 MFMA | bar
//   p4: -                         | stage B1(buf0, 2i+2) + vmcnt(4) | bar | MFMA | bar
//   p5..p8: same on buf1, staging A(buf0,2i+2) @p5, B0/B1(buf1,2i+3) @p7/p8,
//           vmcnt(4) @p8.
// Every half-tile is staged >=1 barrier after its last LDS read and forced
// landed by a vmcnt fence >=1 barrier before its first read.  vmcnt never
// drains to 0 in the main loop (loads stay in flight across barriers, T3+T4).
//
// LDS: linear dest for global_load_lds; swizzle applied to the GLOBAL source
// (granule (l&7)^(l>>3)) and undone at ds_read (g ^ (row&7)) -> conflict-free
// b128 reads (each 8-lane group covers a permutation of the 8 bank-groups).
#define BAR()       asm volatile("s_barrier" ::: "memory")
#define FENCE4()    asm volatile("s_waitcnt vmcnt(4)" ::: "memory")
#define FENCE_ALL() asm volatile("s_waitcnt vmcnt(0)" ::: "memory")

#define MFMAQ(AH, BC, MO, NO)                                              \
  _Pragma("unroll") for (int m2 = 0; m2 < 4; ++m2)                         \
  _Pragma("unroll") for (int n2 = 0; n2 < 2; ++n2)                         \
  _Pragma("unroll") for (int kk = 0; kk < 2; ++kk)                         \
    acc[(MO) + m2][(NO) + n2] = __builtin_amdgcn_mfma_f32_16x16x32_bf16(   \
        (AH)[m2][kk], (BC)[n2][kk], acc[(MO) + m2][(NO) + n2], 0, 0, 0);

__device__ __forceinline__ void gemm256_core(
    const bf16* __restrict__ Ag,   // block's first A row (ld = DIM)
    const bf16* __restrict__ Bg,   // block's first B row (B^T layout, ld = DIM)
    f32x4 acc[8][4])
{
  __shared__ __align__(16) bf16 As[2 * 256 * 64];   // 64 KiB
  __shared__ __align__(16) bf16 Bs[2 * 256 * 64];   // 64 KiB

  const int tid  = threadIdx.x;
  const int lane = tid & 63;
  const int w    = tid >> 6;
  const int l15  = lane & 15;
  const int quad = lane >> 4;
  const int wr2  = (w >> 2) * 128;      // wave row offset (2 M-waves)
  const int wc2  = (w & 3) * 64;        // wave col offset (4 N-waves)

  // staging: thread -> (row srow, swizzled source granule)
  const int srow = w * 8 + (lane >> 3);                 // 0..63
  const int sg8  = ((lane & 7) ^ (lane >> 3)) * 8;      // inverse-swz src gran
  const bf16* gA = Ag + (size_t)srow * DIM + sg8;
  const bf16* gB = Bg + (size_t)srow * DIM + sg8;
  bf16* lA = As + w * 512;              // wave-uniform LDS dest base
  bf16* lB = Bs + w * 512;

  // read-side offsets
  const int g0   = (quad ^ (l15 & 7)) * 8;   // kk=0 granule (swizzled)
  const int g1   = g0 ^ 32;                  // kk=1 granule
  const int aOff = (wr2 + l15) * 64;
  const int bOff = (wc2 + l15) * 64;

#define STAGE_A(b, kt)                                                     \
  { _Pragma("unroll") for (int hh = 0; hh < 2; ++hh)                       \
    _Pragma("unroll") for (int j = 0; j < 2; ++j)                          \
      async_g2l16(gA + (size_t)(hh * 128 + j * 64) * DIM + (kt) * 64,      \
                  lA + (b) * 16384 + (hh * 128 + j * 64) * 64); }
#define STAGE_B0(b, kt)                                                    \
  { _Pragma("unroll") for (int j = 0; j < 2; ++j)                          \
      async_g2l16(gB + (size_t)(j * 64) * DIM + (kt) * 64,                 \
                  lB + (b) * 16384 + (j * 64) * 64); }
#define STAGE_B1(b, kt)                                                    \
  { _Pragma("unroll") for (int j = 0; j < 2; ++j)                          \
      async_g2l16(gB + (size_t)(128 + j * 64) * DIM + (kt) * 64,           \
                  lB + (b) * 16384 + (128 + j * 64) * 64); }

#define LDA(b, rh, m2, gk) \
  (*(const bf16x8*)(As + (b) * 16384 + aOff + (rh) * 4096 + (m2) * 1024 + (gk)))
#define LDB(b, ch, n2, gk) \
  (*(const bf16x8*)(Bs + (b) * 16384 + bOff + (ch) * 2048 + (n2) * 1024 + (gk)))

  const f32x4 vz = {0.f, 0.f, 0.f, 0.f};
#pragma unroll
  for (int mi = 0; mi < 8; ++mi)
#pragma unroll
    for (int ni = 0; ni < 4; ++ni) acc[mi][ni] = vz;

  // prologue: tile0 -> buf0 (8 loads), tile1 B -> buf1 (4 loads);
  // vmcnt(4) forces buf0 landed, leaves buf1's B in flight (steady state).
  STAGE_A(0, 0); STAGE_B0(0, 0); STAGE_B1(0, 0);
  STAGE_B0(1, 1); STAGE_B1(1, 1);
  FENCE4();
  BAR();

  for (int i = 0; i < 32; ++i) {
    const int ktn0 = (2 * i + 2 > 63) ? 63 : 2 * i + 2;  // clamped (dummy @i=31)
    const int ktn1 = (2 * i + 3 > 63) ? 63 : 2 * i + 3;
    // ---------------- half 0: compute buf0 (K-tile 2i) ----------------
    {
      bf16x8 aH[4][2], bC0[2][2], bC1[2][2];
#pragma unroll
      for (int m2 = 0; m2 < 4; ++m2) { aH[m2][0] = LDA(0, 0, m2, g0); aH[m2][1] = LDA(0, 0, m2, g1); }
#pragma unroll
      for (int n2 = 0; n2 < 2; ++n2) { bC0[n2][0] = LDB(0, 0, n2, g0); bC0[n2][1] = LDB(0, 0, n2, g1); }
      STAGE_A(1, 2 * i + 1);
      BAR(); __builtin_amdgcn_s_setprio(1);
      MFMAQ(aH, bC0, 0, 0);
      __builtin_amdgcn_s_setprio(0); BAR();
      // p2
#pragma unroll
      for (int n2 = 0; n2 < 2; ++n2) { bC1[n2][0] = LDB(0, 1, n2, g0); bC1[n2][1] = LDB(0, 1, n2, g1); }
      BAR(); __builtin_amdgcn_s_setprio(1);
      MFMAQ(aH, bC1, 0, 2);
      __builtin_amdgcn_s_setprio(0); BAR();
      // p3
#pragma unroll
      for (int m2 = 0; m2 < 4; ++m2) { aH[m2][0] = LDA(0, 1, m2, g0); aH[m2][1] = LDA(0, 1, m2, g1); }
      STAGE_B0(0, ktn0);
      BAR(); __builtin_amdgcn_s_setprio(1);
      MFMAQ(aH, bC1, 4, 2);
      __builtin_amdgcn_s_setprio(0); BAR();
      // p4
      STAGE_B1(0, ktn0);
      FENCE4();
      BAR(); __builtin_amdgcn_s_setprio(1);
      MFMAQ(aH, bC0, 4, 0);
      __builtin_amdgcn_s_setprio(0); BAR();
    }
    // ---------------- half 1: compute buf1 (K-tile 2i+1) ----------------
    {
      bf16x8 aH[4][2], bC0[2][2], bC1[2][2];
#pragma unroll
      for (int m2 = 0; m2 < 4; ++m2) { aH[m2][0] = LDA(1, 0, m2, g0); aH[m2][1] = LDA(1, 0, m2, g1); }
#pragma unroll
      for (int n2 = 0; n2 < 2; ++n2) { bC0[n2][0] = LDB(1, 0, n2, g0); bC0[n2][1] = LDB(1, 0, n2, g1); }
      STAGE_A(0, ktn0);
      BAR(); __builtin_amdgcn_s_setprio(1);
      MFMAQ(aH, bC0, 0, 0);
      __builtin_amdgcn_s_setprio(0); BAR();
      // p6
#pragma unroll
      for (int n2 = 0; n2 < 2; ++n2) { bC1[n2][0] = LDB(1, 1, n2, g0); bC1[n2][1] = LDB(1, 1, n2, g1); }
      BAR(); __builtin_amdgcn_s_setprio(1);
      MFMAQ(aH, bC1, 0, 2);
      __builtin_amdgcn_s_setprio(0); BAR();
      // p7
#pragma unroll
      for (int m2 = 0; m2 < 4; ++m2) { aH[m2][0] = LDA(1, 1, m2, g0); aH[m2][1] = LDA(1, 1, m2, g1); }
      STAGE_B0(1, ktn1);
      BAR(); __builtin_amdgcn_s_setprio(1);
      MFMAQ(aH, bC1, 4, 2);
      __builtin_amdgcn_s_setprio(0); BAR();
      // p8
      STAGE_B1(1, ktn1);
      FENCE4();
      BAR(); __builtin_amdgcn_s_setprio(1);
      MFMAQ(aH, bC0, 4, 0);
      __builtin_amdgcn_s_setprio(0); BAR();
    }
  }
  // drain dummy prefetches before LDS could be handed to a successor block
  FENCE_ALL();
}

// ---------------------------------------------------------------------------
// QKV projection, 256x256 tiles.  grid = 192 (mTile = bid&7 so each XCD keeps
// one A row-panel in its L2).  nTile<16: Q heads; <20: K; else V.
__global__ __launch_bounds__(512, 2) void qkv256_kernel(
    const bf16* __restrict__ xb, const bf16* __restrict__ wqb,
    const bf16* __restrict__ wkb, const bf16* __restrict__ wvb,
    const float* __restrict__ fc, const float* __restrict__ fs,
    bf16* __restrict__ Qb, bf16* __restrict__ Kb, bf16* __restrict__ Vt)
{
  const int bid   = blockIdx.x;
  const int mTile = bid & 7;
  const int nTile = bid >> 3;
  const bf16* Bg;
  if (nTile < 16)      Bg = wqb + (size_t)nTile * 256 * DIM;
  else if (nTile < 20) Bg = wkb + (size_t)(nTile - 16) * 256 * DIM;
  else                 Bg = wvb + (size_t)(nTile - 20) * 256 * DIM;

  f32x4 acc[8][4];
  gemm256_core(xb + (size_t)mTile * 256 * DIM, Bg, acc);

  const int tid  = threadIdx.x;
  const int lane = tid & 63;
  const int w    = tid >> 6;
  const int l15  = lane & 15;
  const int quad = lane >> 4;
  const int wr2  = (w >> 2) * 128;
  const int wc2  = (w & 3) * 64;
  const int sBase = mTile * 256 + wr2 + quad * 4;
  const int nBase = nTile * 256 + wc2;

  if (nTile < 20) {
    // RoPE: d and d^1 live in adjacent lanes (l15 bit0) -> shfl_xor(1)
    const bool isQ = nTile < 16;
    bf16* dst      = isQ ? Qb : Kb;
    const int ldd  = isQ ? DIM : KVD;
    const float sc = isQ ? SCALE : 1.0f;
    const int cOff = isQ ? nBase : nBase - 4096;
    const int odd  = l15 & 1;
#pragma unroll
    for (int mi = 0; mi < 8; ++mi)
#pragma unroll
      for (int ni = 0; ni < 4; ++ni) {
        const int n    = nBase + ni * 16 + l15;
        const int fidx = (n >> 1) & 63;
        const int col  = cOff + ni * 16 + l15;
#pragma unroll
        for (int r = 0; r < 4; ++r) {
          const int s = sBase + mi * 16 + r;
          float v  = acc[mi][ni][r];
          float pv = __shfl_xor(v, 1, 64);
          float c  = fc[s * 64 + fidx];
          float sn = fs[s * 64 + fidx];
          float o  = odd ? (pv * sn + v * c) : (v * c - pv * sn);
          dst[(size_t)s * ldd + col] = (bf16)(o * sc);
        }
      }
  } else {
    // V: transpose to [kv][d][s]; 4 consecutive rows (s) -> bf16x4 store
    const int vBase = nBase - 5120;
#pragma unroll
    for (int mi = 0; mi < 8; ++mi) {
      const int sb = sBase + mi * 16;
#pragma unroll
      for (int ni = 0; ni < 4; ++ni) {
        const int nv = vBase + ni * 16 + l15;
        const int t = nv >> 7, d = nv & 127;
        bf16x4 pv;
#pragma unroll
        for (int r = 0; r < 4; ++r) pv[r] = (bf16)acc[mi][ni][r];
        *(bf16x4*)(Vt + ((size_t)t * HD + d) * SEQ + sb) = pv;
      }
    }
  }
}

// Output projection: attn(2048x4096 bf16) @ wo^T -> out (fp32), 256x256 tiles
__global__ __launch_bounds__(512, 2) void out256_kernel(
    const bf16* __restrict__ attnb, const bf16* __restrict__ wob,
    float* __restrict__ out)
{
  const int bid   = blockIdx.x;
  const int mTile = bid & 7;
  const int nTile = bid >> 3;

  f32x4 acc[8][4];
  gemm256_core(attnb + (size_t)mTile * 256 * DIM,
               wob + (size_t)nTile * 256 * DIM, acc);

  const int tid  = threadIdx.x;
  const int lane = tid & 63;
  const int w    = tid >> 6;
  const int l15  = lane & 15;
  const int quad = lane >> 4;
  const int wr2  = (w >> 2) * 128;
  const int wc2  = (w & 3) * 64;
  const int sBase = mTile * 256 + wr2 + quad * 4;
#pragma unroll
  for (int mi = 0; mi < 8; ++mi)
#pragma unroll
    for (int ni = 0; ni < 4; ++ni) {
      const int col = nTile * 256 + wc2 + ni * 16 + l15;
#pragma unroll
      for (int r = 0; r < 4; ++r)
        out[(size_t)(sBase + mi * 16 + r) * DIM + col] = acc[mi][ni][r];
    }
}

// ---------------------------------------------------------------------------
// Flash attention: transposed scores (St = K @ Q^T). Unchanged.
__global__ __launch_bounds__(256, 2) void attn_kernel(
    const bf16* __restrict__ Qb, const bf16* __restrict__ Kb,
    const bf16* __restrict__ Vt, bf16* __restrict__ attnb)
{
  __shared__ __align__(16) bf16 Ks[64 * 128];   // [key][hd], swizzled 16B grps
  __shared__ __align__(16) bf16 Vs[128 * 64];   // [hd][key], swizzled
  __shared__ __align__(16) bf16 Ps[128 * 64];   // [query][key], swizzled

  const int b    = blockIdx.x;
  const int half = b >> 8;
  const int r8   = b & 255;
  const int h    = (half << 4) | (r8 >> 4);
  const int qt   = half ? (r8 & 15) : 15 - (r8 & 15);
  const int kvh  = h >> 2;
  const int qbase = qt * 128;

  const int tid  = threadIdx.x;
  const int lane = tid & 63;
  const int w    = tid >> 6;
  const int l15  = lane & 15;
  const int quad = lane >> 4;

  bf16x8 qfrag[2][4];
#pragma unroll
  for (int n = 0; n < 2; ++n) {
    int q = qbase + w * 32 + n * 16 + l15;
#pragma unroll
    for (int ks = 0; ks < 4; ++ks)
      qfrag[n][ks] = *(const bf16x8*)(Qb + (size_t)q * DIM + h * HD +
                                      ks * 32 + quad * 8);
  }

  const f32x4 vzero = {0.f, 0.f, 0.f, 0.f};
  f32x4 oacc[8][2];
#pragma unroll
  for (int dm = 0; dm < 8; ++dm)
#pragma unroll
    for (int n = 0; n < 2; ++n) oacc[dm][n] = vzero;
  float m_run[2] = {-1e30f, -1e30f};
  float l_run[2] = {0.f, 0.f};

  const int nkt = 2 * (qt + 1);
  for (int kt = 0; kt < nkt; ++kt) {
    const int kbase = kt * 64;

    __syncthreads();
#pragma unroll
    for (int t = 0; t < 4; ++t) {
      int kr0 = w * 16 + t * 4;
      int krow = kr0 + (lane >> 4);
      int kg = (lane & 15) ^ (krow & 7);
      async_g2l16(Kb + (size_t)(kbase + krow) * KVD + kvh * HD + kg * 8,
                  Ks + kr0 * 128);
      int vr0 = w * 32 + t * 8;
      int d = vr0 + (lane >> 3);
      int vg = (lane & 7) ^ (d & 7);
      async_g2l16(Vt + ((size_t)kvh * HD + d) * SEQ + kbase + vg * 8,
                  Vs + vr0 * 64);
    }
    __syncthreads();

    f32x4 sacc[4][2];
#pragma unroll
    for (int kg = 0; kg < 4; ++kg)
#pragma unroll
      for (int n = 0; n < 2; ++n) sacc[kg][n] = vzero;
#pragma unroll
    for (int kg = 0; kg < 4; ++kg) {
      bf16x8 kf[4];
#pragma unroll
      for (int ks = 0; ks < 4; ++ks) {
        int row = kg * 16 + l15;
        kf[ks] = *(const bf16x8*)(Ks + row * 128 +
                                  (((ks * 4 + quad) ^ (row & 7)) * 8));
      }
#pragma unroll
      for (int n = 0; n < 2; ++n)
#pragma unroll
        for (int ks = 0; ks < 4; ++ks)
          sacc[kg][n] = __builtin_amdgcn_mfma_f32_16x16x32_bf16(
              kf[ks], qfrag[n][ks], sacc[kg][n], 0, 0, 0);
    }

#pragma unroll
    for (int n = 0; n < 2; ++n) {
      const int qloc = w * 32 + n * 16 + l15;
      const int qglob = qbase + qloc;
      if (kbase + 63 > qbase + w * 32 + n * 16) {
#pragma unroll
        for (int kg = 0; kg < 4; ++kg)
#pragma unroll
          for (int r = 0; r < 4; ++r) {
            int key = kbase + kg * 16 + quad * 4 + r;
            if (key > qglob) sacc[kg][n][r] = NEGBIG;
          }
      }
      float mx = -1e30f;
#pragma unroll
      for (int kg = 0; kg < 4; ++kg)
#pragma unroll
        for (int r = 0; r < 4; ++r) mx = fmaxf(mx, sacc[kg][n][r]);
      mx = fmaxf(mx, __shfl_xor(mx, 16, 64));
      mx = fmaxf(mx, __shfl_xor(mx, 32, 64));
      float mnew = fmaxf(m_run[n], mx);
      float alpha = __expf(m_run[n] - mnew);
      m_run[n] = mnew;
      float rs = 0.f;
#pragma unroll
      for (int kg = 0; kg < 4; ++kg) {
        bf16x4 pk;
#pragma unroll
        for (int r = 0; r < 4; ++r) {
          float p = __expf(sacc[kg][n][r] - mnew);
          rs += p;
          pk[r] = (bf16)p;
        }
        int g16 = (kg * 2 + (quad >> 1)) ^ (qloc & 7);
        *(bf16x4*)(Ps + qloc * 64 + g16 * 8 + (quad & 1) * 4) = pk;
      }
      rs += __shfl_xor(rs, 16, 64);
      rs += __shfl_xor(rs, 32, 64);
      l_run[n] = alpha * l_run[n] + rs;
#pragma unroll
      for (int dm = 0; dm < 8; ++dm)
#pragma unroll
        for (int r = 0; r < 4; ++r) oacc[dm][n][r] *= alpha;
    }

    bf16x8 pf[2][2];
#pragma unroll
    for (int kk = 0; kk < 2; ++kk)
#pragma unroll
      for (int n = 0; n < 2; ++n) {
        int qloc = w * 32 + n * 16 + l15;
        pf[kk][n] = *(const bf16x8*)(Ps + qloc * 64 +
                                     (((kk * 4 + quad) ^ (qloc & 7)) * 8));
      }
#pragma unroll
    for (int dm = 0; dm < 8; ++dm) {
#pragma unroll
      for (int kk = 0; kk < 2; ++kk) {
        int d = dm * 16 + l15;
        bf16x8 vf = *(const bf16x8*)(Vs + d * 64 +
                                     (((kk * 4 + quad) ^ (d & 7)) * 8));
#pragma unroll
        for (int n = 0; n < 2; ++n)
          oacc[dm][n] = __builtin_amdgcn_mfma_f32_16x16x32_bf16(
              vf, pf[kk][n], oacc[dm][n], 0, 0, 0);
      }
    }
  }

#pragma unroll
  for (int n = 0; n < 2; ++n) {
    float inv = 1.0f / l_run[n];
    int q = qbase + w * 32 + n * 16 + l15;
#pragma unroll
    for (int dm = 0; dm < 8; ++dm) {
      bf16x4 ov;
#pragma unroll
      for (int r = 0; r < 4; ++r) ov[r] = (bf16)(oacc[dm][n][r] * inv);
      *(bf16x4*)(attnb + (size_t)q * DIM + h * HD + dm * 16 + quad * 4) = ov;
    }
  }
}

// ---------------------------------------------------------------------------
extern "C" void kernel_launch(void* const* d_in, const int* in_sizes, int n_in,
                              void* d_out, int out_size, void* d_ws, size_t ws_size,
                              hipStream_t stream) {
  const float* x  = (const float*)d_in[0];
  const float* wq = (const float*)d_in[1];
  const float* wk = (const float*)d_in[2];
  const float* wv = (const float*)d_in[3];
  const float* wo = (const float*)d_in[4];
  const float* fc = (const float*)d_in[5];
  const float* fs = (const float*)d_in[6];
  float* out = (float*)d_out;

  size_t off = 0;
  char* wsb = (char*)d_ws;
  auto take = [&](size_t bytes) -> void* {
    void* p = wsb + off;
    off += (bytes + 255) & ~(size_t)255;
    return p;
  };
  bf16*  xb    = (bf16*)take((size_t)SEQ * DIM * 2);
  bf16*  wqb   = (bf16*)take((size_t)DIM * DIM * 2);
  bf16*  wkb   = (bf16*)take((size_t)KVD * DIM * 2);
  bf16*  wvb   = (bf16*)take((size_t)KVD * DIM * 2);
  bf16*  wob   = (bf16*)take((size_t)DIM * DIM * 2);
  bf16*  Qb    = (bf16*)take((size_t)SEQ * DIM * 2);
  bf16*  Kb    = (bf16*)take((size_t)SEQ * KVD * 2);
  bf16*  Vt    = (bf16*)take((size_t)NKV * HD * SEQ * 2);
  bf16*  attnb = (bf16*)take((size_t)SEQ * DIM * 2);

  // fused cast (1 launch, 12.6M float4)
  cast_all_kernel<<<C4 / 256, 256, 0, stream>>>(x, wq, wk, wv, wo,
                                                xb, wqb, wkb, wvb, wob);

  // fused QKV projection + RoPE/scale/V-transpose epilogue, 256^2 8-phase
  qkv256_kernel<<<dim3(192), 512, 0, stream>>>(xb, wqb, wkb, wvb,
                                               fc, fs, Qb, Kb, Vt);

  // flash attention (512 linear blocks, big/small qt pairing)
  attn_kernel<<<dim3(512), 256, 0, stream>>>(Qb, Kb, Vt, attnb);

  // output projection, 256^2 8-phase
  out256_kernel<<<dim3(128), 512, 0, stream>>>(attnb, wob, out);
}

// Round 2
// 491.616 us; speedup vs baseline: 1.0408x; 1.0408x over previous
//
#include <hip/hip_runtime.h>
#include <hip/hip_bf16.h>
#include <math.h>

// Problem constants
#define SEQ 2048
#define DIM 4096
#define NH 32
#define NKV 8
#define HD 128
#define KVD 1024              // NKV*HD
#define SCALE 0.08838834764831845f
#define NEGBIG -1000000000.0f

typedef __bf16 bf16;
typedef __attribute__((ext_vector_type(4))) __bf16 bf16x4;
typedef __attribute__((ext_vector_type(8))) __bf16 bf16x8;
typedef __attribute__((ext_vector_type(4))) float f32x4;

// ---------------------------------------------------------------------------
// async global->LDS 16B copy (wave-uniform LDS base + lane*16 semantics)
__device__ __forceinline__ void async_g2l16(const bf16* g, bf16* l) {
  __builtin_amdgcn_global_load_lds(
      (const __attribute__((address_space(1))) void*)g,
      (__attribute__((address_space(3))) void*)l,
      16, 0, 0);
}

// ---------------------------------------------------------------------------
// fused fp32 -> bf16 cast for all 5 tensors, float4 vectorized, 1 launch
#define SEG_X  2097152            // SEQ*DIM/4
#define SEG_WQ 4194304            // DIM*DIM/4
#define SEG_WK 1048576            // KVD*DIM/4
#define C0SEG SEG_X
#define C1SEG (C0SEG + SEG_WQ)
#define C2SEG (C1SEG + SEG_WK)
#define C3SEG (C2SEG + SEG_WK)
#define C4SEG (C3SEG + SEG_WQ)    // 12582912 total float4

__global__ void cast_all_kernel(const float* __restrict__ x,
                                const float* __restrict__ wq,
                                const float* __restrict__ wk,
                                const float* __restrict__ wv,
                                const float* __restrict__ wo,
                                bf16* __restrict__ xb, bf16* __restrict__ wqb,
                                bf16* __restrict__ wkb, bf16* __restrict__ wvb,
                                bf16* __restrict__ wob) {
  int i = blockIdx.x * 256 + threadIdx.x;
  const float* src; bf16* dst; int j;
  if (i < C0SEG)      { src = x;  dst = xb;  j = i; }
  else if (i < C1SEG) { src = wq; dst = wqb; j = i - C0SEG; }
  else if (i < C2SEG) { src = wk; dst = wkb; j = i - C1SEG; }
  else if (i < C3SEG) { src = wv; dst = wvb; j = i - C2SEG; }
  else                { src = wo; dst = wob; j = i - C3SEG; }
  float4 v = ((const float4*)src)[j];
  bf16x4 o;
  o[0] = (bf16)v.x; o[1] = (bf16)v.y; o[2] = (bf16)v.z; o[3] = (bf16)v.w;
  ((bf16x4*)dst)[j] = o;
}

// ---------------------------------------------------------------------------
// BM=256 x BN=(64*NF) tile, BK=64, 8 waves (2M x 4N), 4-phase counted-vmcnt
// K-loop.  Per-wave output 128 x (16*NF).  NF=3 -> BN=192 (qkv, grid 8x32);
// NF=2 -> BN=128 (out-proj, grid 8x32).  Loads/K-tile = 4(A) + NF(B); steady
// fence = vmcnt(4+NF): forces tile t+1's staging (issued 4-7 phases earlier),
// leaves tile t+2's in flight.  Never drains in the main loop.
//
// Per K-tile t (buf b = t&1), Gray quadrant order:
//   p1: ds_read aH(rh0) 8 + bC0 2*C0  | -               | BAR | MFMA rh0xch0 | BAR
//   p2: ds_read bC1 2               | -                 | BAR | MFMA rh0xch1 | BAR
//   p3: ds_read aH(rh1) 8           | stage B(b, t+2)   | BAR | MFMA rh1xch1 | BAR
//   p4: -                           | stage A(b, t+2);
//                                     vmcnt(4+NF)       | BAR | MFMA rh1xch0 | BAR
// Invariants: a buffer region is staged only >=1 barrier after its last
// ds_read completed (reads drain at the lgkmcnt(0) before that phase's MFMA);
// staged data is read only >=1 barrier after the staging wave's forcing fence.
//
// LDS: linear dest for global_load_lds; swizzle applied to the GLOBAL source
// (granule (l&7)^(l>>3)) and undone at ds_read (granule ^ (row&7)) ->
// conflict-free b128 reads.
#define BAR()       asm volatile("s_barrier" ::: "memory")
#define FENCE_ALL() asm volatile("s_waitcnt vmcnt(0)" ::: "memory")

template<int NF>
__device__ __forceinline__ void gemm256_core(
    const bf16* __restrict__ Ag,   // block's first A row (ld = DIM)
    const bf16* __restrict__ Bg,   // block's first B row (B^T layout, ld = DIM)
    f32x4 acc[8][NF])
{
  constexpr int C0F  = NF - (NF >> 1);       // ch0 frags: NF=3 -> 2, NF=2 -> 1
  constexpr int BUFB = NF * 4096;            // B double-buffer stride (elems)
  __shared__ __align__(16) bf16 As[2 * 256 * 64];
  __shared__ __align__(16) bf16 Bs[2 * BUFB];

  const int tid  = threadIdx.x;
  const int lane = tid & 63;
  const int w    = tid >> 6;
  const int l15  = lane & 15;
  const int quad = lane >> 4;
  const int wr2  = (w >> 2) * 128;           // wave row offset (2 M-waves)
  const int wc3  = (w & 3) * (16 * NF);      // wave col offset (4 N-waves)

  // staging: thread -> (row srow, inverse-swizzled source granule)
  const int srow = w * 8 + (lane >> 3);                 // 0..63 per 64-row call
  const int sg8  = ((lane & 7) ^ (lane >> 3)) * 8;
  const bf16* gA = Ag + (size_t)srow * DIM + sg8;
  const bf16* gB = Bg + (size_t)srow * DIM + sg8;
  bf16* lA = As + w * 512;                   // wave-uniform LDS dest base
  bf16* lB = Bs + w * 512;

  // read-side swizzled granules
  const int g0   = (quad ^ (l15 & 7)) * 8;
  const int g1   = g0 ^ 32;
  const int aOff = (wr2 + l15) * 64;
  const int bOff = (wc3 + l15) * 64;

  auto stageA = [&](int b, int kt) {
#pragma unroll
    for (int j = 0; j < 4; ++j)
      async_g2l16(gA + (size_t)(j * 64) * DIM + kt * 64,
                  lA + b * 16384 + j * 4096);
  };
  auto stageB = [&](int b, int kt) {
#pragma unroll
    for (int j = 0; j < NF; ++j)
      async_g2l16(gB + (size_t)(j * 64) * DIM + kt * 64,
                  lB + b * BUFB + j * 4096);
  };
  auto fence_steady = [] {
    if constexpr (NF == 3) asm volatile("s_waitcnt vmcnt(7)" ::: "memory");
    else                   asm volatile("s_waitcnt vmcnt(6)" ::: "memory");
  };

  const f32x4 vz = {0.f, 0.f, 0.f, 0.f};
#pragma unroll
  for (int mi = 0; mi < 8; ++mi)
#pragma unroll
    for (int ni = 0; ni < NF; ++ni) acc[mi][ni] = vz;

  auto ktile = [&](int b, int kt2) {
    const bf16* Ab = As + b * 16384;
    const bf16* Bb = Bs + b * BUFB;
    bf16x8 aH[4][2], bc0[C0F][2], bc1[2];
    // ---- p1: A rh0 + B ch0 reads; MFMA rh0 x ch0
#pragma unroll
    for (int m2 = 0; m2 < 4; ++m2) {
      aH[m2][0] = *(const bf16x8*)(Ab + aOff + m2 * 1024 + g0);
      aH[m2][1] = *(const bf16x8*)(Ab + aOff + m2 * 1024 + g1);
    }
#pragma unroll
    for (int n = 0; n < C0F; ++n) {
      bc0[n][0] = *(const bf16x8*)(Bb + bOff + n * 1024 + g0);
      bc0[n][1] = *(const bf16x8*)(Bb + bOff + n * 1024 + g1);
    }
    BAR(); __builtin_amdgcn_s_setprio(1);
#pragma unroll
    for (int m2 = 0; m2 < 4; ++m2)
#pragma unroll
      for (int n = 0; n < C0F; ++n)
#pragma unroll
        for (int kk = 0; kk < 2; ++kk)
          acc[m2][n] = __builtin_amdgcn_mfma_f32_16x16x32_bf16(
              aH[m2][kk], bc0[n][kk], acc[m2][n], 0, 0, 0);
    __builtin_amdgcn_s_setprio(0); BAR();
    // ---- p2: B ch1 reads; MFMA rh0 x ch1
    bc1[0] = *(const bf16x8*)(Bb + bOff + C0F * 1024 + g0);
    bc1[1] = *(const bf16x8*)(Bb + bOff + C0F * 1024 + g1);
    BAR(); __builtin_amdgcn_s_setprio(1);
#pragma unroll
    for (int m2 = 0; m2 < 4; ++m2)
#pragma unroll
      for (int kk = 0; kk < 2; ++kk)
        acc[m2][C0F] = __builtin_amdgcn_mfma_f32_16x16x32_bf16(
            aH[m2][kk], bc1[kk], acc[m2][C0F], 0, 0, 0);
    __builtin_amdgcn_s_setprio(0); BAR();
    // ---- p3: A rh1 reads + stage B(t+2); MFMA rh1 x ch1
#pragma unroll
    for (int m2 = 0; m2 < 4; ++m2) {
      aH[m2][0] = *(const bf16x8*)(Ab + aOff + 4096 + m2 * 1024 + g0);
      aH[m2][1] = *(const bf16x8*)(Ab + aOff + 4096 + m2 * 1024 + g1);
    }
    stageB(b, kt2);
    BAR(); __builtin_amdgcn_s_setprio(1);
#pragma unroll
    for (int m2 = 0; m2 < 4; ++m2)
#pragma unroll
      for (int kk = 0; kk < 2; ++kk)
        acc[4 + m2][C0F] = __builtin_amdgcn_mfma_f32_16x16x32_bf16(
            aH[m2][kk], bc1[kk], acc[4 + m2][C0F], 0, 0, 0);
    __builtin_amdgcn_s_setprio(0); BAR();
    // ---- p4: stage A(t+2) + steady fence; MFMA rh1 x ch0
    stageA(b, kt2);
    fence_steady();
    BAR(); __builtin_amdgcn_s_setprio(1);
#pragma unroll
    for (int m2 = 0; m2 < 4; ++m2)
#pragma unroll
      for (int n = 0; n < C0F; ++n)
#pragma unroll
        for (int kk = 0; kk < 2; ++kk)
          acc[4 + m2][n] = __builtin_amdgcn_mfma_f32_16x16x32_bf16(
              aH[m2][kk], bc0[n][kk], acc[4 + m2][n], 0, 0, 0);
    __builtin_amdgcn_s_setprio(0); BAR();
  };

  // prologue: tiles 0,1 staged; fence forces tile 0, leaves tile 1 in flight
  stageB(0, 0); stageA(0, 0); stageB(1, 1); stageA(1, 1);
  fence_steady();
  BAR();

#pragma unroll 1
  for (int t = 0; t < 64; t += 2) {
    const int k2a = (t + 2 < 64) ? t + 2 : 63;   // clamped dummy at tail
    const int k2b = (t + 3 < 64) ? t + 3 : 63;
    ktile(0, k2a);
    ktile(1, k2b);
  }
  FENCE_ALL();   // drain dummy tail prefetches
}

// ---------------------------------------------------------------------------
// QKV projection, 256x192 tiles, grid 8x32 = 256 blocks (1/CU, all CUs).
// mTile = bid&7: each XCD keeps one x row-panel (2 MB) in its L2.
// B rows come from the CONTIGUOUS wq|wk|wv workspace region (sizes are
// multiples of 256 B so take() inserts no padding).  Epilogue branches per
// 16-col group: Q (<4096, RoPE*SCALE), K (<5120, RoPE), V (transpose).
__global__ __launch_bounds__(512, 2) void qkv256_kernel(
    const bf16* __restrict__ xb, const bf16* __restrict__ wqkv,
    const float* __restrict__ fc, const float* __restrict__ fs,
    bf16* __restrict__ Qb, bf16* __restrict__ Kb, bf16* __restrict__ Vt)
{
  const int bid   = blockIdx.x;
  const int mTile = bid & 7;
  const int nTile = bid >> 3;        // 0..31

  f32x4 acc[8][3];
  gemm256_core<3>(xb + (size_t)mTile * 256 * DIM,
                  wqkv + (size_t)nTile * 192 * DIM, acc);

  const int tid  = threadIdx.x;
  const int lane = tid & 63;
  const int w    = tid >> 6;
  const int l15  = lane & 15;
  const int quad = lane >> 4;
  const int wr2  = (w >> 2) * 128;
  const int wc3  = (w & 3) * 48;
  const int sBase = mTile * 256 + wr2 + quad * 4;
  const int nBase = nTile * 192 + wc3;
  const int odd  = l15 & 1;

#pragma unroll
  for (int ni = 0; ni < 3; ++ni) {
    const int c16 = nBase + ni * 16;     // wave-uniform 16-col group base
    const int col = c16 + l15;
    if (c16 < 5120) {
      // Q or K: RoPE (d, d^1 in adjacent lanes -> shfl_xor(1))
      const bool isQ = c16 < 4096;
      bf16* dst      = isQ ? Qb : Kb;
      const int ldd  = isQ ? DIM : KVD;
      const float sc = isQ ? SCALE : 1.0f;
      const int cc   = isQ ? col : col - 4096;
      const int fidx = (col >> 1) & 63;
#pragma unroll
      for (int mi = 0; mi < 8; ++mi) {
#pragma unroll
        for (int r = 0; r < 4; ++r) {
          const int s = sBase + mi * 16 + r;
          float v  = acc[mi][ni][r];
          float pv = __shfl_xor(v, 1, 64);
          float c  = fc[s * 64 + fidx];
          float sn = fs[s * 64 + fidx];
          float o  = odd ? (pv * sn + v * c) : (v * c - pv * sn);
          dst[(size_t)s * ldd + cc] = (bf16)(o * sc);
        }
      }
    } else {
      // V: transpose to [kv][d][s]; 4 consecutive rows (s) -> bf16x4 store
      const int cv = col - 5120;
      const int t = cv >> 7, d = cv & 127;
#pragma unroll
      for (int mi = 0; mi < 8; ++mi) {
        bf16x4 pv;
#pragma unroll
        for (int r = 0; r < 4; ++r) pv[r] = (bf16)acc[mi][ni][r];
        *(bf16x4*)(Vt + ((size_t)t * HD + d) * SEQ + sBase + mi * 16) = pv;
      }
    }
  }
}

// Output projection: attn(2048x4096 bf16) @ wo^T -> out (fp32).
// 256x128 tiles, grid 8x32 = 256 blocks (1/CU, all CUs).
__global__ __launch_bounds__(512, 2) void out256_kernel(
    const bf16* __restrict__ attnb, const bf16* __restrict__ wob,
    float* __restrict__ out)
{
  const int bid   = blockIdx.x;
  const int mTile = bid & 7;
  const int nTile = bid >> 3;        // 0..31

  f32x4 acc[8][2];
  gemm256_core<2>(attnb + (size_t)mTile * 256 * DIM,
                  wob + (size_t)nTile * 128 * DIM, acc);

  const int tid  = threadIdx.x;
  const int lane = tid & 63;
  const int w    = tid >> 6;
  const int l15  = lane & 15;
  const int quad = lane >> 4;
  const int wr2  = (w >> 2) * 128;
  const int wc3  = (w & 3) * 32;
  const int sBase = mTile * 256 + wr2 + quad * 4;
  const int cBase = nTile * 128 + wc3;
#pragma unroll
  for (int mi = 0; mi < 8; ++mi)
#pragma unroll
    for (int ni = 0; ni < 2; ++ni) {
      const int col = cBase + ni * 16 + l15;
#pragma unroll
      for (int r = 0; r < 4; ++r)
        out[(size_t)(sBase + mi * 16 + r) * DIM + col] = acc[mi][ni][r];
    }
}

// ---------------------------------------------------------------------------
// Flash attention: transposed scores (St = K @ Q^T). Unchanged.
__global__ __launch_bounds__(256, 2) void attn_kernel(
    const bf16* __restrict__ Qb, const bf16* __restrict__ Kb,
    const bf16* __restrict__ Vt, bf16* __restrict__ attnb)
{
  __shared__ __align__(16) bf16 Ks[64 * 128];   // [key][hd], swizzled 16B grps
  __shared__ __align__(16) bf16 Vs[128 * 64];   // [hd][key], swizzled
  __shared__ __align__(16) bf16 Ps[128 * 64];   // [query][key], swizzled

  const int b    = blockIdx.x;
  const int half = b >> 8;
  const int r8   = b & 255;
  const int h    = (half << 4) | (r8 >> 4);
  const int qt   = half ? (r8 & 15) : 15 - (r8 & 15);
  const int kvh  = h >> 2;
  const int qbase = qt * 128;

  const int tid  = threadIdx.x;
  const int lane = tid & 63;
  const int w    = tid >> 6;
  const int l15  = lane & 15;
  const int quad = lane >> 4;

  bf16x8 qfrag[2][4];
#pragma unroll
  for (int n = 0; n < 2; ++n) {
    int q = qbase + w * 32 + n * 16 + l15;
#pragma unroll
    for (int ks = 0; ks < 4; ++ks)
      qfrag[n][ks] = *(const bf16x8*)(Qb + (size_t)q * DIM + h * HD +
                                      ks * 32 + quad * 8);
  }

  const f32x4 vzero = {0.f, 0.f, 0.f, 0.f};
  f32x4 oacc[8][2];
#pragma unroll
  for (int dm = 0; dm < 8; ++dm)
#pragma unroll
    for (int n = 0; n < 2; ++n) oacc[dm][n] = vzero;
  float m_run[2] = {-1e30f, -1e30f};
  float l_run[2] = {0.f, 0.f};

  const int nkt = 2 * (qt + 1);
  for (int kt = 0; kt < nkt; ++kt) {
    const int kbase = kt * 64;

    __syncthreads();
#pragma unroll
    for (int t = 0; t < 4; ++t) {
      int kr0 = w * 16 + t * 4;
      int krow = kr0 + (lane >> 4);
      int kg = (lane & 15) ^ (krow & 7);
      async_g2l16(Kb + (size_t)(kbase + krow) * KVD + kvh * HD + kg * 8,
                  Ks + kr0 * 128);
      int vr0 = w * 32 + t * 8;
      int d = vr0 + (lane >> 3);
      int vg = (lane & 7) ^ (d & 7);
      async_g2l16(Vt + ((size_t)kvh * HD + d) * SEQ + kbase + vg * 8,
                  Vs + vr0 * 64);
    }
    __syncthreads();

    f32x4 sacc[4][2];
#pragma unroll
    for (int kg = 0; kg < 4; ++kg)
#pragma unroll
      for (int n = 0; n < 2; ++n) sacc[kg][n] = vzero;
#pragma unroll
    for (int kg = 0; kg < 4; ++kg) {
      bf16x8 kf[4];
#pragma unroll
      for (int ks = 0; ks < 4; ++ks) {
        int row = kg * 16 + l15;
        kf[ks] = *(const bf16x8*)(Ks + row * 128 +
                                  (((ks * 4 + quad) ^ (row & 7)) * 8));
      }
#pragma unroll
      for (int n = 0; n < 2; ++n)
#pragma unroll
        for (int ks = 0; ks < 4; ++ks)
          sacc[kg][n] = __builtin_amdgcn_mfma_f32_16x16x32_bf16(
              kf[ks], qfrag[n][ks], sacc[kg][n], 0, 0, 0);
    }

#pragma unroll
    for (int n = 0; n < 2; ++n) {
      const int qloc = w * 32 + n * 16 + l15;
      const int qglob = qbase + qloc;
      if (kbase + 63 > qbase + w * 32 + n * 16) {
#pragma unroll
        for (int kg = 0; kg < 4; ++kg)
#pragma unroll
          for (int r = 0; r < 4; ++r) {
            int key = kbase + kg * 16 + quad * 4 + r;
            if (key > qglob) sacc[kg][n][r] = NEGBIG;
          }
      }
      float mx = -1e30f;
#pragma unroll
      for (int kg = 0; kg < 4; ++kg)
#pragma unroll
        for (int r = 0; r < 4; ++r) mx = fmaxf(mx, sacc[kg][n][r]);
      mx = fmaxf(mx, __shfl_xor(mx, 16, 64));
      mx = fmaxf(mx, __shfl_xor(mx, 32, 64));
      float mnew = fmaxf(m_run[n], mx);
      float alpha = __expf(m_run[n] - mnew);
      m_run[n] = mnew;
      float rs = 0.f;
#pragma unroll
      for (int kg = 0; kg < 4; ++kg) {
        bf16x4 pk;
#pragma unroll
        for (int r = 0; r < 4; ++r) {
          float p = __expf(sacc[kg][n][r] - mnew);
          rs += p;
          pk[r] = (bf16)p;
        }
        int g16 = (kg * 2 + (quad >> 1)) ^ (qloc & 7);
        *(bf16x4*)(Ps + qloc * 64 + g16 * 8 + (quad & 1) * 4) = pk;
      }
      rs += __shfl_xor(rs, 16, 64);
      rs += __shfl_xor(rs, 32, 64);
      l_run[n] = alpha * l_run[n] + rs;
#pragma unroll
      for (int dm = 0; dm < 8; ++dm)
#pragma unroll
        for (int r = 0; r < 4; ++r) oacc[dm][n][r] *= alpha;
    }

    bf16x8 pf[2][2];
#pragma unroll
    for (int kk = 0; kk < 2; ++kk)
#pragma unroll
      for (int n = 0; n < 2; ++n) {
        int qloc = w * 32 + n * 16 + l15;
        pf[kk][n] = *(const bf16x8*)(Ps + qloc * 64 +
                                     (((kk * 4 + quad) ^ (qloc & 7)) * 8));
      }
#pragma unroll
    for (int dm = 0; dm < 8; ++dm) {
#pragma unroll
      for (int kk = 0; kk < 2; ++kk) {
        int d = dm * 16 + l15;
        bf16x8 vf = *(const bf16x8*)(Vs + d * 64 +
                                     (((kk * 4 + quad) ^ (d & 7)) * 8));
#pragma unroll
        for (int n = 0; n < 2; ++n)
          oacc[dm][n] = __builtin_amdgcn_mfma_f32_16x16x32_bf16(
              vf, pf[kk][n], oacc[dm][n], 0, 0, 0);
      }
    }
  }

#pragma unroll
  for (int n = 0; n < 2; ++n) {
    float inv = 1.0f / l_run[n];
    int q = qbase + w * 32 + n * 16 + l15;
#pragma unroll
    for (int dm = 0; dm < 8; ++dm) {
      bf16x4 ov;
#pragma unroll
      for (int r = 0; r < 4; ++r) ov[r] = (bf16)(oacc[dm][n][r] * inv);
      *(bf16x4*)(attnb + (size_t)q * DIM + h * HD + dm * 16 + quad * 4) = ov;
    }
  }
}

// ---------------------------------------------------------------------------
extern "C" void kernel_launch(void* const* d_in, const int* in_sizes, int n_in,
                              void* d_out, int out_size, void* d_ws, size_t ws_size,
                              hipStream_t stream) {
  const float* x  = (const float*)d_in[0];
  const float* wq = (const float*)d_in[1];
  const float* wk = (const float*)d_in[2];
  const float* wv = (const float*)d_in[3];
  const float* wo = (const float*)d_in[4];
  const float* fc = (const float*)d_in[5];
  const float* fs = (const float*)d_in[6];
  float* out = (float*)d_out;

  size_t off = 0;
  char* wsb = (char*)d_ws;
  auto take = [&](size_t bytes) -> void* {
    void* p = wsb + off;
    off += (bytes + 255) & ~(size_t)255;
    return p;
  };
  // NOTE: wqb/wkb/wvb must stay adjacent takes (all sizes are multiples of
  // 256 B, so no padding): qkv256_kernel indexes them as ONE contiguous
  // [6144][4096] bf16 matrix.
  bf16*  xb    = (bf16*)take((size_t)SEQ * DIM * 2);
  bf16*  wqb   = (bf16*)take((size_t)DIM * DIM * 2);
  bf16*  wkb   = (bf16*)take((size_t)KVD * DIM * 2);
  bf16*  wvb   = (bf16*)take((size_t)KVD * DIM * 2);
  bf16*  wob   = (bf16*)take((size_t)DIM * DIM * 2);
  bf16*  Qb    = (bf16*)take((size_t)SEQ * DIM * 2);
  bf16*  Kb    = (bf16*)take((size_t)SEQ * KVD * 2);
  bf16*  Vt    = (bf16*)take((size_t)NKV * HD * SEQ * 2);
  bf16*  attnb = (bf16*)take((size_t)SEQ * DIM * 2);

  // fused cast (1 launch, 12.6M float4)
  cast_all_kernel<<<C4SEG / 256, 256, 0, stream>>>(x, wq, wk, wv, wo,
                                                   xb, wqb, wkb, wvb, wob);

  // fused QKV projection + RoPE/scale/V-transpose epilogue (256x192, 256 wg)
  qkv256_kernel<<<dim3(256), 512, 0, stream>>>(xb, wqb, fc, fs, Qb, Kb, Vt);

  // flash attention (512 linear blocks, big/small qt pairing)
  attn_kernel<<<dim3(512), 256, 0, stream>>>(Qb, Kb, Vt, attnb);

  // output projection (256x128, 256 wg)
  out256_kernel<<<dim3(256), 512, 0, stream>>>(attnb, wob, out);
}

// Round 3
// 462.103 us; speedup vs baseline: 1.1072x; 1.0639x over previous
//
#include <hip/hip_runtime.h>
#include <hip/hip_bf16.h>
#include <math.h>

// Problem constants
#define SEQ 2048
#define DIM 4096
#define NH 32
#define NKV 8
#define HD 128
#define KVD 1024              // NKV*HD
#define SCALE 0.08838834764831845f
#define NEGBIG -1000000000.0f

typedef __bf16 bf16;
typedef __attribute__((ext_vector_type(4))) __bf16 bf16x4;
typedef __attribute__((ext_vector_type(8))) __bf16 bf16x8;
typedef __attribute__((ext_vector_type(4))) float f32x4;

// ---------------------------------------------------------------------------
// async global->LDS 16B copy (wave-uniform LDS base + lane*16 semantics)
__device__ __forceinline__ void async_g2l16(const bf16* g, bf16* l) {
  __builtin_amdgcn_global_load_lds(
      (const __attribute__((address_space(1))) void*)g,
      (__attribute__((address_space(3))) void*)l,
      16, 0, 0);
}

// ---------------------------------------------------------------------------
// fused fp32 -> bf16 cast for x, wq, wk, wv (wo is cast inside qkv256's idle
// blocks).  float4 vectorized, 1 launch.
#define SEG_X  2097152            // SEQ*DIM/4
#define SEG_WQ 4194304            // DIM*DIM/4
#define SEG_WK 1048576            // KVD*DIM/4
#define CX0 SEG_X
#define CX1 (CX0 + SEG_WQ)
#define CX2 (CX1 + SEG_WK)
#define CX3 (CX2 + SEG_WK)        // 8388608 total float4

__global__ void cast_all_kernel(const float* __restrict__ x,
                                const float* __restrict__ wq,
                                const float* __restrict__ wk,
                                const float* __restrict__ wv,
                                bf16* __restrict__ xb, bf16* __restrict__ wqb,
                                bf16* __restrict__ wkb, bf16* __restrict__ wvb) {
  int i = blockIdx.x * 256 + threadIdx.x;
  const float* src; bf16* dst; int j;
  if (i < CX0)      { src = x;  dst = xb;  j = i; }
  else if (i < CX1) { src = wq; dst = wqb; j = i - CX0; }
  else if (i < CX2) { src = wk; dst = wkb; j = i - CX1; }
  else              { src = wv; dst = wvb; j = i - CX2; }
  float4 v = ((const float4*)src)[j];
  bf16x4 o;
  o[0] = (bf16)v.x; o[1] = (bf16)v.y; o[2] = (bf16)v.z; o[3] = (bf16)v.w;
  ((bf16x4*)dst)[j] = o;
}

// ---------------------------------------------------------------------------
// 256x256 tile, BK=64, 8-wave (2Mx4N), 8-phase counted-vmcnt GEMM core.
// (R1 core, measured 4.09 TF/CU — best per-CU variant so far.)
#define BAR()       asm volatile("s_barrier" ::: "memory")
#define FENCE4()    asm volatile("s_waitcnt vmcnt(4)" ::: "memory")
#define FENCE_ALL() asm volatile("s_waitcnt vmcnt(0)" ::: "memory")

#define MFMAQ(AH, BC, MO, NO)                                              \
  _Pragma("unroll") for (int m2 = 0; m2 < 4; ++m2)                         \
  _Pragma("unroll") for (int n2 = 0; n2 < 2; ++n2)                         \
  _Pragma("unroll") for (int kk = 0; kk < 2; ++kk)                         \
    acc[(MO) + m2][(NO) + n2] = __builtin_amdgcn_mfma_f32_16x16x32_bf16(   \
        (AH)[m2][kk], (BC)[n2][kk], acc[(MO) + m2][(NO) + n2], 0, 0, 0);

__device__ __forceinline__ void gemm256_core(
    const bf16* __restrict__ Ag,   // block's first A row (ld = DIM)
    const bf16* __restrict__ Bg,   // block's first B row (B^T layout, ld = DIM)
    f32x4 acc[8][4])
{
  __shared__ __align__(16) bf16 As[2 * 256 * 64];   // 64 KiB
  __shared__ __align__(16) bf16 Bs[2 * 256 * 64];   // 64 KiB

  const int tid  = threadIdx.x;
  const int lane = tid & 63;
  const int w    = tid >> 6;
  const int l15  = lane & 15;
  const int quad = lane >> 4;
  const int wr2  = (w >> 2) * 128;      // wave row offset (2 M-waves)
  const int wc2  = (w & 3) * 64;        // wave col offset (4 N-waves)

  // staging: thread -> (row srow, swizzled source granule)
  const int srow = w * 8 + (lane >> 3);                 // 0..63
  const int sg8  = ((lane & 7) ^ (lane >> 3)) * 8;      // inverse-swz src gran
  const bf16* gA = Ag + (size_t)srow * DIM + sg8;
  const bf16* gB = Bg + (size_t)srow * DIM + sg8;
  bf16* lA = As + w * 512;              // wave-uniform LDS dest base
  bf16* lB = Bs + w * 512;

  // read-side offsets
  const int g0   = (quad ^ (l15 & 7)) * 8;   // kk=0 granule (swizzled)
  const int g1   = g0 ^ 32;                  // kk=1 granule
  const int aOff = (wr2 + l15) * 64;
  const int bOff = (wc2 + l15) * 64;

#define STAGE_A(b, kt)                                                     \
  { _Pragma("unroll") for (int hh = 0; hh < 2; ++hh)                       \
    _Pragma("unroll") for (int j = 0; j < 2; ++j)                          \
      async_g2l16(gA + (size_t)(hh * 128 + j * 64) * DIM + (kt) * 64,      \
                  lA + (b) * 16384 + (hh * 128 + j * 64) * 64); }
#define STAGE_B0(b, kt)                                                    \
  { _Pragma("unroll") for (int j = 0; j < 2; ++j)                          \
      async_g2l16(gB + (size_t)(j * 64) * DIM + (kt) * 64,                 \
                  lB + (b) * 16384 + (j * 64) * 64); }
#define STAGE_B1(b, kt)                                                    \
  { _Pragma("unroll") for (int j = 0; j < 2; ++j)                          \
      async_g2l16(gB + (size_t)(128 + j * 64) * DIM + (kt) * 64,           \
                  lB + (b) * 16384 + (128 + j * 64) * 64); }

#define LDA(b, rh, m2, gk) \
  (*(const bf16x8*)(As + (b) * 16384 + aOff + (rh) * 4096 + (m2) * 1024 + (gk)))
#define LDB(b, ch, n2, gk) \
  (*(const bf16x8*)(Bs + (b) * 16384 + bOff + (ch) * 2048 + (n2) * 1024 + (gk)))

  const f32x4 vz = {0.f, 0.f, 0.f, 0.f};
#pragma unroll
  for (int mi = 0; mi < 8; ++mi)
#pragma unroll
    for (int ni = 0; ni < 4; ++ni) acc[mi][ni] = vz;

  // prologue: tile0 -> buf0 (8 loads), tile1 B -> buf1 (4 loads);
  // vmcnt(4) forces buf0 landed, leaves buf1's B in flight (steady state).
  STAGE_A(0, 0); STAGE_B0(0, 0); STAGE_B1(0, 0);
  STAGE_B0(1, 1); STAGE_B1(1, 1);
  FENCE4();
  BAR();

  for (int i = 0; i < 32; ++i) {
    const int ktn0 = (2 * i + 2 > 63) ? 63 : 2 * i + 2;  // clamped (dummy @i=31)
    const int ktn1 = (2 * i + 3 > 63) ? 63 : 2 * i + 3;
    // ---------------- half 0: compute buf0 (K-tile 2i) ----------------
    {
      bf16x8 aH[4][2], bC0[2][2], bC1[2][2];
#pragma unroll
      for (int m2 = 0; m2 < 4; ++m2) { aH[m2][0] = LDA(0, 0, m2, g0); aH[m2][1] = LDA(0, 0, m2, g1); }
#pragma unroll
      for (int n2 = 0; n2 < 2; ++n2) { bC0[n2][0] = LDB(0, 0, n2, g0); bC0[n2][1] = LDB(0, 0, n2, g1); }
      STAGE_A(1, 2 * i + 1);
      BAR(); __builtin_amdgcn_s_setprio(1);
      MFMAQ(aH, bC0, 0, 0);
      __builtin_amdgcn_s_setprio(0); BAR();
      // p2
#pragma unroll
      for (int n2 = 0; n2 < 2; ++n2) { bC1[n2][0] = LDB(0, 1, n2, g0); bC1[n2][1] = LDB(0, 1, n2, g1); }
      BAR(); __builtin_amdgcn_s_setprio(1);
      MFMAQ(aH, bC1, 0, 2);
      __builtin_amdgcn_s_setprio(0); BAR();
      // p3
#pragma unroll
      for (int m2 = 0; m2 < 4; ++m2) { aH[m2][0] = LDA(0, 1, m2, g0); aH[m2][1] = LDA(0, 1, m2, g1); }
      STAGE_B0(0, ktn0);
      BAR(); __builtin_amdgcn_s_setprio(1);
      MFMAQ(aH, bC1, 4, 2);
      __builtin_amdgcn_s_setprio(0); BAR();
      // p4
      STAGE_B1(0, ktn0);
      FENCE4();
      BAR(); __builtin_amdgcn_s_setprio(1);
      MFMAQ(aH, bC0, 4, 0);
      __builtin_amdgcn_s_setprio(0); BAR();
    }
    // ---------------- half 1: compute buf1 (K-tile 2i+1) ----------------
    {
      bf16x8 aH[4][2], bC0[2][2], bC1[2][2];
#pragma unroll
      for (int m2 = 0; m2 < 4; ++m2) { aH[m2][0] = LDA(1, 0, m2, g0); aH[m2][1] = LDA(1, 0, m2, g1); }
#pragma unroll
      for (int n2 = 0; n2 < 2; ++n2) { bC0[n2][0] = LDB(1, 0, n2, g0); bC0[n2][1] = LDB(1, 0, n2, g1); }
      STAGE_A(0, ktn0);
      BAR(); __builtin_amdgcn_s_setprio(1);
      MFMAQ(aH, bC0, 0, 0);
      __builtin_amdgcn_s_setprio(0); BAR();
      // p6
#pragma unroll
      for (int n2 = 0; n2 < 2; ++n2) { bC1[n2][0] = LDB(1, 1, n2, g0); bC1[n2][1] = LDB(1, 1, n2, g1); }
      BAR(); __builtin_amdgcn_s_setprio(1);
      MFMAQ(aH, bC1, 0, 2);
      __builtin_amdgcn_s_setprio(0); BAR();
      // p7
#pragma unroll
      for (int m2 = 0; m2 < 4; ++m2) { aH[m2][0] = LDA(1, 1, m2, g0); aH[m2][1] = LDA(1, 1, m2, g1); }
      STAGE_B0(1, ktn1);
      BAR(); __builtin_amdgcn_s_setprio(1);
      MFMAQ(aH, bC1, 4, 2);
      __builtin_amdgcn_s_setprio(0); BAR();
      // p8
      STAGE_B1(1, ktn1);
      FENCE4();
      BAR(); __builtin_amdgcn_s_setprio(1);
      MFMAQ(aH, bC0, 4, 0);
      __builtin_amdgcn_s_setprio(0); BAR();
    }
  }
  // drain dummy tail prefetches
  FENCE_ALL();
}

// ---------------------------------------------------------------------------
// QKV projection, 256x256 tiles, grid 256 = 192 GEMM blocks (8 mTile x 24
// nTile; mTile=bid&7 keeps one x row-panel per XCD-L2) + 64 blocks that cast
// wo -> wob (free CUs; wob is first consumed by out_gemm, two launches later).
__global__ __launch_bounds__(512, 2) void qkv256_kernel(
    const bf16* __restrict__ xb, const bf16* __restrict__ wqb,
    const bf16* __restrict__ wkb, const bf16* __restrict__ wvb,
    const float* __restrict__ wo, bf16* __restrict__ wob,
    const float* __restrict__ fc, const float* __restrict__ fs,
    bf16* __restrict__ Qb, bf16* __restrict__ Kb, bf16* __restrict__ Vt)
{
  const int bid = blockIdx.x;
  const int tid = threadIdx.x;
  if (bid >= 192) {
    // wo cast: 4194304 float4 over 64 blocks x 512 threads (no barriers)
    for (int j = (bid - 192) * 512 + tid; j < SEG_WQ; j += 64 * 512) {
      float4 v = ((const float4*)wo)[j];
      bf16x4 o;
      o[0] = (bf16)v.x; o[1] = (bf16)v.y; o[2] = (bf16)v.z; o[3] = (bf16)v.w;
      ((bf16x4*)wob)[j] = o;
    }
    return;
  }
  const int mTile = bid & 7;
  const int nTile = bid >> 3;        // 0..23
  const bf16* Bg;
  if (nTile < 16)      Bg = wqb + (size_t)nTile * 256 * DIM;
  else if (nTile < 20) Bg = wkb + (size_t)(nTile - 16) * 256 * DIM;
  else                 Bg = wvb + (size_t)(nTile - 20) * 256 * DIM;

  f32x4 acc[8][4];
  gemm256_core(xb + (size_t)mTile * 256 * DIM, Bg, acc);

  const int lane = tid & 63;
  const int w    = tid >> 6;
  const int l15  = lane & 15;
  const int quad = lane >> 4;
  const int wr2  = (w >> 2) * 128;
  const int wc2  = (w & 3) * 64;
  const int sBase = mTile * 256 + wr2 + quad * 4;
  const int nBase = nTile * 256 + wc2;

  if (nTile < 20) {
    // RoPE: d and d^1 live in adjacent lanes (l15 bit0) -> shfl_xor(1)
    const bool isQ = nTile < 16;
    bf16* dst      = isQ ? Qb : Kb;
    const int ldd  = isQ ? DIM : KVD;
    const float sc = isQ ? SCALE : 1.0f;
    const int cOff = isQ ? nBase : nBase - 4096;
    const int odd  = l15 & 1;
#pragma unroll
    for (int mi = 0; mi < 8; ++mi)
#pragma unroll
      for (int ni = 0; ni < 4; ++ni) {
        const int n    = nBase + ni * 16 + l15;
        const int fidx = (n >> 1) & 63;
        const int col  = cOff + ni * 16 + l15;
#pragma unroll
        for (int r = 0; r < 4; ++r) {
          const int s = sBase + mi * 16 + r;
          float v  = acc[mi][ni][r];
          float pv = __shfl_xor(v, 1, 64);
          float c  = fc[s * 64 + fidx];
          float sn = fs[s * 64 + fidx];
          float o  = odd ? (pv * sn + v * c) : (v * c - pv * sn);
          dst[(size_t)s * ldd + col] = (bf16)(o * sc);
        }
      }
  } else {
    // V: transpose to [kv][d][s]; 4 consecutive rows (s) -> bf16x4 store
    const int vBase = nBase - 5120;
#pragma unroll
    for (int mi = 0; mi < 8; ++mi) {
      const int sb = sBase + mi * 16;
#pragma unroll
      for (int ni = 0; ni < 4; ++ni) {
        const int nv = vBase + ni * 16 + l15;
        const int t = nv >> 7, d = nv & 127;
        bf16x4 pv;
#pragma unroll
        for (int r = 0; r < 4; ++r) pv[r] = (bf16)acc[mi][ni][r];
        *(bf16x4*)(Vt + ((size_t)t * HD + d) * SEQ + sb) = pv;
      }
    }
  }
}

// ---------------------------------------------------------------------------
// m97-style 128x128 B^T GEMM core (2 blocks/CU; measured-best for out-proj).
// LDS[row][g] holds global k-group g ^ ((row>>1)&3); swizzle applied to the
// GLOBAL source address at staging and undone at fragment read (involution).
__device__ __forceinline__ void gemm128_core(
    const bf16* __restrict__ A, int lda,
    const bf16* __restrict__ B, int ldb,
    int K, int mBase, f32x4 acc[4][4])
{
  __shared__ __align__(16) bf16 As[128 * 32];
  __shared__ __align__(16) bf16 Bs[128 * 32];

  const int tid  = threadIdx.x;
  const int lane = tid & 63;
  const int w    = tid >> 6;
  const int l15  = lane & 15;
  const int quad = lane >> 4;
  const int wr   = (w >> 1) * 64;
  const int wc   = (w & 1) * 64;

  const int srow = lane >> 2;                      // 0..15 within chunk
  const int kswz = ((lane & 3) ^ ((srow >> 1) & 3)) * 8;  // swizzled k-group
  const bf16* gA0 = A + (size_t)(mBase + w * 16 + srow) * lda + kswz;
  const bf16* gA1 = gA0 + (size_t)64 * lda;
  const bf16* gB0 = B + (size_t)(w * 16 + srow) * ldb + kswz;
  const bf16* gB1 = gB0 + (size_t)64 * ldb;
  bf16* lA0 = As + w * 512;
  bf16* lA1 = As + (w + 4) * 512;
  bf16* lB0 = Bs + w * 512;
  bf16* lB1 = Bs + (w + 4) * 512;

  const f32x4 vzero = {0.f, 0.f, 0.f, 0.f};
#pragma unroll
  for (int mi = 0; mi < 4; ++mi)
#pragma unroll
    for (int ni = 0; ni < 4; ++ni) acc[mi][ni] = vzero;

  const int rsw = ((l15 >> 1) & 3);                // read-side swizzle term

  for (int k0 = 0; k0 < K; k0 += 32) {
    __syncthreads();
    async_g2l16(gA0 + k0, lA0);
    async_g2l16(gA1 + k0, lA1);
    async_g2l16(gB0 + k0, lB0);
    async_g2l16(gB1 + k0, lB1);
    __syncthreads();

    bf16x8 a[4], b[4];
#pragma unroll
    for (int mi = 0; mi < 4; ++mi)
      a[mi] = *(const bf16x8*)(As + (wr + mi * 16 + l15) * 32 +
                               ((quad ^ rsw) * 8));
#pragma unroll
    for (int ni = 0; ni < 4; ++ni)
      b[ni] = *(const bf16x8*)(Bs + (wc + ni * 16 + l15) * 32 +
                               ((quad ^ rsw) * 8));
#pragma unroll
    for (int mi = 0; mi < 4; ++mi)
#pragma unroll
      for (int ni = 0; ni < 4; ++ni)
        acc[mi][ni] = __builtin_amdgcn_mfma_f32_16x16x32_bf16(
            a[mi], b[ni], acc[mi][ni], 0, 0, 0);
  }
}

// Output projection: attn(2048x4096 bf16) @ wo^T -> out (fp32), 128x128 tiles
__global__ __launch_bounds__(256, 2) void out_gemm_kernel(
    const bf16* __restrict__ attnb, const bf16* __restrict__ wob,
    float* __restrict__ out)
{
  const int mBase = blockIdx.y * 128;
  f32x4 acc[4][4];
  gemm128_core(attnb, DIM, wob + (size_t)blockIdx.x * 128 * DIM, DIM, DIM,
               mBase, acc);

  const int tid  = threadIdx.x;
  const int lane = tid & 63;
  const int w    = tid >> 6;
  const int l15  = lane & 15;
  const int quad = lane >> 4;
  const int wr   = (w >> 1) * 64;
  const int wc   = (w & 1) * 64;
#pragma unroll
  for (int mi = 0; mi < 4; ++mi) {
    int row = mBase + wr + mi * 16 + quad * 4;
#pragma unroll
    for (int ni = 0; ni < 4; ++ni) {
      int col = blockIdx.x * 128 + wc + ni * 16 + l15;
#pragma unroll
      for (int r = 0; r < 4; ++r)
        out[(size_t)(row + r) * DIM + col] = acc[mi][ni][r];
    }
  }
}

// ---------------------------------------------------------------------------
// Flash attention: transposed scores (St = K @ Q^T). Unchanged.
__global__ __launch_bounds__(256, 2) void attn_kernel(
    const bf16* __restrict__ Qb, const bf16* __restrict__ Kb,
    const bf16* __restrict__ Vt, bf16* __restrict__ attnb)
{
  __shared__ __align__(16) bf16 Ks[64 * 128];   // [key][hd], swizzled 16B grps
  __shared__ __align__(16) bf16 Vs[128 * 64];   // [hd][key], swizzled
  __shared__ __align__(16) bf16 Ps[128 * 64];   // [query][key], swizzled

  const int b    = blockIdx.x;
  const int half = b >> 8;
  const int r8   = b & 255;
  const int h    = (half << 4) | (r8 >> 4);
  const int qt   = half ? (r8 & 15) : 15 - (r8 & 15);
  const int kvh  = h >> 2;
  const int qbase = qt * 128;

  const int tid  = threadIdx.x;
  const int lane = tid & 63;
  const int w    = tid >> 6;
  const int l15  = lane & 15;
  const int quad = lane >> 4;

  bf16x8 qfrag[2][4];
#pragma unroll
  for (int n = 0; n < 2; ++n) {
    int q = qbase + w * 32 + n * 16 + l15;
#pragma unroll
    for (int ks = 0; ks < 4; ++ks)
      qfrag[n][ks] = *(const bf16x8*)(Qb + (size_t)q * DIM + h * HD +
                                      ks * 32 + quad * 8);
  }

  const f32x4 vzero = {0.f, 0.f, 0.f, 0.f};
  f32x4 oacc[8][2];
#pragma unroll
  for (int dm = 0; dm < 8; ++dm)
#pragma unroll
    for (int n = 0; n < 2; ++n) oacc[dm][n] = vzero;
  float m_run[2] = {-1e30f, -1e30f};
  float l_run[2] = {0.f, 0.f};

  const int nkt = 2 * (qt + 1);
  for (int kt = 0; kt < nkt; ++kt) {
    const int kbase = kt * 64;

    __syncthreads();
#pragma unroll
    for (int t = 0; t < 4; ++t) {
      int kr0 = w * 16 + t * 4;
      int krow = kr0 + (lane >> 4);
      int kg = (lane & 15) ^ (krow & 7);
      async_g2l16(Kb + (size_t)(kbase + krow) * KVD + kvh * HD + kg * 8,
                  Ks + kr0 * 128);
      int vr0 = w * 32 + t * 8;
      int d = vr0 + (lane >> 3);
      int vg = (lane & 7) ^ (d & 7);
      async_g2l16(Vt + ((size_t)kvh * HD + d) * SEQ + kbase + vg * 8,
                  Vs + vr0 * 64);
    }
    __syncthreads();

    f32x4 sacc[4][2];
#pragma unroll
    for (int kg = 0; kg < 4; ++kg)
#pragma unroll
      for (int n = 0; n < 2; ++n) sacc[kg][n] = vzero;
#pragma unroll
    for (int kg = 0; kg < 4; ++kg) {
      bf16x8 kf[4];
#pragma unroll
      for (int ks = 0; ks < 4; ++ks) {
        int row = kg * 16 + l15;
        kf[ks] = *(const bf16x8*)(Ks + row * 128 +
                                  (((ks * 4 + quad) ^ (row & 7)) * 8));
      }
#pragma unroll
      for (int n = 0; n < 2; ++n)
#pragma unroll
        for (int ks = 0; ks < 4; ++ks)
          sacc[kg][n] = __builtin_amdgcn_mfma_f32_16x16x32_bf16(
              kf[ks], qfrag[n][ks], sacc[kg][n], 0, 0, 0);
    }

#pragma unroll
    for (int n = 0; n < 2; ++n) {
      const int qloc = w * 32 + n * 16 + l15;
      const int qglob = qbase + qloc;
      if (kbase + 63 > qbase + w * 32 + n * 16) {
#pragma unroll
        for (int kg = 0; kg < 4; ++kg)
#pragma unroll
          for (int r = 0; r < 4; ++r) {
            int key = kbase + kg * 16 + quad * 4 + r;
            if (key > qglob) sacc[kg][n][r] = NEGBIG;
          }
      }
      float mx = -1e30f;
#pragma unroll
      for (int kg = 0; kg < 4; ++kg)
#pragma unroll
        for (int r = 0; r < 4; ++r) mx = fmaxf(mx, sacc[kg][n][r]);
      mx = fmaxf(mx, __shfl_xor(mx, 16, 64));
      mx = fmaxf(mx, __shfl_xor(mx, 32, 64));
      float mnew = fmaxf(m_run[n], mx);
      float alpha = __expf(m_run[n] - mnew);
      m_run[n] = mnew;
      float rs = 0.f;
#pragma unroll
      for (int kg = 0; kg < 4; ++kg) {
        bf16x4 pk;
#pragma unroll
        for (int r = 0; r < 4; ++r) {
          float p = __expf(sacc[kg][n][r] - mnew);
          rs += p;
          pk[r] = (bf16)p;
        }
        int g16 = (kg * 2 + (quad >> 1)) ^ (qloc & 7);
        *(bf16x4*)(Ps + qloc * 64 + g16 * 8 + (quad & 1) * 4) = pk;
      }
      rs += __shfl_xor(rs, 16, 64);
      rs += __shfl_xor(rs, 32, 64);
      l_run[n] = alpha * l_run[n] + rs;
#pragma unroll
      for (int dm = 0; dm < 8; ++dm)
#pragma unroll
        for (int r = 0; r < 4; ++r) oacc[dm][n][r] *= alpha;
    }

    bf16x8 pf[2][2];
#pragma unroll
    for (int kk = 0; kk < 2; ++kk)
#pragma unroll
      for (int n = 0; n < 2; ++n) {
        int qloc = w * 32 + n * 16 + l15;
        pf[kk][n] = *(const bf16x8*)(Ps + qloc * 64 +
                                     (((kk * 4 + quad) ^ (qloc & 7)) * 8));
      }
#pragma unroll
    for (int dm = 0; dm < 8; ++dm) {
#pragma unroll
      for (int kk = 0; kk < 2; ++kk) {
        int d = dm * 16 + l15;
        bf16x8 vf = *(const bf16x8*)(Vs + d * 64 +
                                     (((kk * 4 + quad) ^ (d & 7)) * 8));
#pragma unroll
        for (int n = 0; n < 2; ++n)
          oacc[dm][n] = __builtin_amdgcn_mfma_f32_16x16x32_bf16(
              vf, pf[kk][n], oacc[dm][n], 0, 0, 0);
      }
    }
  }

#pragma unroll
  for (int n = 0; n < 2; ++n) {
    float inv = 1.0f / l_run[n];
    int q = qbase + w * 32 + n * 16 + l15;
#pragma unroll
    for (int dm = 0; dm < 8; ++dm) {
      bf16x4 ov;
#pragma unroll
      for (int r = 0; r < 4; ++r) ov[r] = (bf16)(oacc[dm][n][r] * inv);
      *(bf16x4*)(attnb + (size_t)q * DIM + h * HD + dm * 16 + quad * 4) = ov;
    }
  }
}

// ---------------------------------------------------------------------------
extern "C" void kernel_launch(void* const* d_in, const int* in_sizes, int n_in,
                              void* d_out, int out_size, void* d_ws, size_t ws_size,
                              hipStream_t stream) {
  const float* x  = (const float*)d_in[0];
  const float* wq = (const float*)d_in[1];
  const float* wk = (const float*)d_in[2];
  const float* wv = (const float*)d_in[3];
  const float* wo = (const float*)d_in[4];
  const float* fc = (const float*)d_in[5];
  const float* fs = (const float*)d_in[6];
  float* out = (float*)d_out;

  size_t off = 0;
  char* wsb = (char*)d_ws;
  auto take = [&](size_t bytes) -> void* {
    void* p = wsb + off;
    off += (bytes + 255) & ~(size_t)255;
    return p;
  };
  bf16*  xb    = (bf16*)take((size_t)SEQ * DIM * 2);
  bf16*  wqb   = (bf16*)take((size_t)DIM * DIM * 2);
  bf16*  wkb   = (bf16*)take((size_t)KVD * DIM * 2);
  bf16*  wvb   = (bf16*)take((size_t)KVD * DIM * 2);
  bf16*  wob   = (bf16*)take((size_t)DIM * DIM * 2);
  bf16*  Qb    = (bf16*)take((size_t)SEQ * DIM * 2);
  bf16*  Kb    = (bf16*)take((size_t)SEQ * KVD * 2);
  bf16*  Vt    = (bf16*)take((size_t)NKV * HD * SEQ * 2);
  bf16*  attnb = (bf16*)take((size_t)SEQ * DIM * 2);

  // fused cast of x, wq, wk, wv (wo is cast inside qkv256's spare blocks)
  cast_all_kernel<<<CX3 / 256, 256, 0, stream>>>(x, wq, wk, wv,
                                                 xb, wqb, wkb, wvb);

  // QKV projection (192 GEMM blocks) + wo-cast (64 blocks) in one launch
  qkv256_kernel<<<dim3(256), 512, 0, stream>>>(xb, wqb, wkb, wvb, wo, wob,
                                               fc, fs, Qb, Kb, Vt);

  // flash attention (512 linear blocks, big/small qt pairing)
  attn_kernel<<<dim3(512), 256, 0, stream>>>(Qb, Kb, Vt, attnb);

  // output projection (128^2 tiles, 2 blocks/CU — measured-best structure)
  out_gemm_kernel<<<dim3(32, 16), 256, 0, stream>>>(attnb, wob, out);
}